// Round 5
// baseline (312.644 us; speedup 1.0000x reference)
//
#include <hip/hip_runtime.h>
#include <math.h>

#define BB 32
#define LL 2048
#define DD 64
#define UU 40
#define CC 64            // bf16-phase candidates per batch
#define NSEG 8           // epilogue key segments (256 keys each)
#define PSTR 42          // pT row stride (floats); even -> 8B-aligned b64 ops
#define NEG_BIG (-3.0e38f)

typedef __attribute__((ext_vector_type(8))) short short8;
typedef __attribute__((ext_vector_type(4))) float f32x4;
typedef unsigned long long ull;
typedef unsigned int uint;
typedef unsigned short ushort_t;

__device__ __forceinline__ unsigned short f2bf(float f) {
  uint u = __float_as_uint(f);
  u += 0x7FFFu + ((u >> 16) & 1u);   // RNE
  return (unsigned short)(u >> 16);
}
__device__ __forceinline__ uint fsort(float f) {
  uint u = __float_as_uint(f);
  return (u & 0x80000000u) ? ~u : (u | 0x80000000u);  // monotonic map
}
__device__ __forceinline__ ull shfl_xor_u64(ull x, int m) {
  uint lo = (uint)x, hi = (uint)(x >> 32);
  lo = __shfl_xor(lo, m);
  hi = __shfl_xor(hi, m);
  return ((ull)hi << 32) | lo;
}
__device__ __forceinline__ int4 pack_bf16x8(float4 a, float4 c4) {
  int4 o;
  o.x = (int)(f2bf(a.x) | ((uint)f2bf(a.y) << 16));
  o.y = (int)(f2bf(a.z) | ((uint)f2bf(a.w) << 16));
  o.z = (int)(f2bf(c4.x) | ((uint)f2bf(c4.y) << 16));
  o.w = (int)(f2bf(c4.z) | ((uint)f2bf(c4.w) << 16));
  return o;
}

// ---------------------------------------------------------------------------
// Kernel 1: partial Ksum over gathered rows. Kpart[b][p][d].
// ---------------------------------------------------------------------------
__global__ __launch_bounds__(256) void ksum_kernel(const float* __restrict__ K,
                                                   const int* __restrict__ idx,
                                                   float* __restrict__ Kpart) {
  int p = blockIdx.x, b = blockIdx.y, tid = threadIdx.x;
  int d = tid & 63, c = tid >> 6;
  const float* Kb = K + (size_t)b * LL * DD;
  float acc = 0.f;
  int j0 = p * 128 + c * 32;
#pragma unroll 4
  for (int t = 0; t < 32; ++t) acc += Kb[(size_t)idx[j0 + t] * DD + d];
  __shared__ float red[256];
  red[tid] = acc;
  __syncthreads();
  if (c == 0) Kpart[(b * 16 + p) * 64 + d] = red[d] + red[64 + d] + red[128 + d] + red[192 + d];
}

// ---------------------------------------------------------------------------
// Kernel 2: bf16 MFMA M-scores with INLINE fp32->bf16 conversion in staging
// (prep pass eliminated). Mb[b][q] = max_j(Q.K_sample[j]) - (Q.Ksum)/L.
// ---------------------------------------------------------------------------
__global__ __launch_bounds__(256) void mfma_m_kernel(const float* __restrict__ Q,
                                                     const float* __restrict__ K,
                                                     const int* __restrict__ idx,
                                                     const float* __restrict__ Kpart,
                                                     float* __restrict__ Mb) {
  __shared__ __align__(16) ushort_t Qs[128 * 64];  // 16 KB, swizzled
  __shared__ __align__(16) ushort_t Ks[128 * 64];  // 16 KB, swizzled
  __shared__ float Mmax[2][128];
  __shared__ float KsumS[64];

  int b = blockIdx.y, q0 = blockIdx.x * 128;
  int t = threadIdx.x;
  int w = t >> 6, L = t & 63;

  if (t < 64) {
    float s = 0.f;
#pragma unroll
    for (int p = 0; p < 16; ++p) s += Kpart[(b * 16 + p) * 64 + t];
    KsumS[t] = s;
  }

  // stage Q tile once: read fp32, convert to bf16, swizzled store
  {
    int g = t & 7;
#pragma unroll
    for (int it = 0; it < 4; ++it) {
      int r = it * 32 + (t >> 3);
      const float* src = Q + ((size_t)b * LL + q0 + r) * DD + g * 8;
      float4 a = *(const float4*)src;
      float4 c4 = *(const float4*)(src + 4);
      *(int4*)&Qs[r * 64 + 8 * (g ^ (r & 7))] = pack_bf16x8(a, c4);
    }
  }

  f32x4 mx[4];
#pragma unroll
  for (int i = 0; i < 4; ++i) mx[i] = (f32x4){NEG_BIG, NEG_BIG, NEG_BIG, NEG_BIG};

  const int waveQ = 64 * (w & 1);
  const int waveK = 64 * (w >> 1);
  const int lm = L & 15;
  const int lq = L >> 4;

  for (int c = 0; c < LL / 128; ++c) {
    __syncthreads();
    {
      int g = t & 7;
#pragma unroll
      for (int it = 0; it < 4; ++it) {
        int r = it * 32 + (t >> 3);
        int gk = idx[c * 128 + r];
        const float* src = K + ((size_t)b * LL + gk) * DD + g * 8;
        float4 a = *(const float4*)src;
        float4 c4 = *(const float4*)(src + 4);
        *(int4*)&Ks[r * 64 + 8 * (g ^ (r & 7))] = pack_bf16x8(a, c4);
      }
    }
    __syncthreads();

    f32x4 acc[4][4];
#pragma unroll
    for (int i = 0; i < 4; ++i)
#pragma unroll
      for (int j = 0; j < 4; ++j) acc[i][j] = (f32x4){0.f, 0.f, 0.f, 0.f};

#pragma unroll
    for (int s = 0; s < 2; ++s) {
      int g = 4 * s + lq;
      short8 A[4];
#pragma unroll
      for (int qt = 0; qt < 4; ++qt) {
        int r = waveQ + 16 * qt + lm;
        A[qt] = *(const short8*)&Qs[r * 64 + 8 * (g ^ (r & 7))];
      }
#pragma unroll
      for (int kt = 0; kt < 4; ++kt) {
        int rB = waveK + 16 * kt + lm;
        short8 Bf = *(const short8*)&Ks[rB * 64 + 8 * (g ^ (rB & 7))];
#pragma unroll
        for (int qt = 0; qt < 4; ++qt) {
          acc[qt][kt] = __builtin_amdgcn_mfma_f32_16x16x32_bf16(A[qt], Bf, acc[qt][kt], 0, 0, 0);
        }
      }
    }
#pragma unroll
    for (int qt = 0; qt < 4; ++qt)
#pragma unroll
      for (int kt = 0; kt < 4; ++kt) {
#pragma unroll
        for (int r4 = 0; r4 < 4; ++r4) mx[qt][r4] = fmaxf(mx[qt][r4], acc[qt][kt][r4]);
      }
  }

#pragma unroll
  for (int qt = 0; qt < 4; ++qt) {
#pragma unroll
    for (int r4 = 0; r4 < 4; ++r4) {
      float v = mx[qt][r4];
      v = fmaxf(v, __shfl_xor(v, 1));
      v = fmaxf(v, __shfl_xor(v, 2));
      v = fmaxf(v, __shfl_xor(v, 4));
      v = fmaxf(v, __shfl_xor(v, 8));
      mx[qt][r4] = v;
    }
  }
  if (lm < 4) {
    int qt = lm;
#pragma unroll
    for (int r4 = 0; r4 < 4; ++r4) {
      Mmax[w >> 1][waveQ + 16 * qt + 4 * lq + r4] = mx[qt][r4];
    }
  }
  __syncthreads();

  if (t < 128) {
    float m = fmaxf(Mmax[0][t], Mmax[1][t]);
    const float4* Qr = (const float4*)(Q + ((size_t)b * LL + q0 + t) * DD);
    float s = 0.f;
#pragma unroll
    for (int i = 0; i < 16; ++i) {
      float4 qv = Qr[i];
      s += qv.x * KsumS[4 * i] + qv.y * KsumS[4 * i + 1] + qv.z * KsumS[4 * i + 2] +
           qv.w * KsumS[4 * i + 3];
    }
    Mb[b * LL + q0 + t] = m - s * (1.0f / (float)LL);
  }
}

// ---------------------------------------------------------------------------
// Kernel 3: per-batch top-64 candidate set by Mb (set only; any order).
// ---------------------------------------------------------------------------
__global__ __launch_bounds__(256) void cand_kernel(const float* __restrict__ Mb,
                                                   int* __restrict__ cand) {
  int b = blockIdx.x, t = threadIdx.x;
  int w = t >> 6;
  float v[8];
#pragma unroll
  for (int i = 0; i < 8; ++i) v[i] = Mb[b * LL + t + 256 * i];
  __shared__ ull warr[4];
  __shared__ ull winls;
  for (int round = 0; round < CC; ++round) {
    float bv = v[0];
    int bi = 0;
#pragma unroll
    for (int i = 1; i < 8; ++i)
      if (v[i] > bv) { bv = v[i]; bi = i; }
    ull key = ((ull)fsort(bv) << 32) | (ull)(uint)(t + 256 * bi);
#pragma unroll
    for (int m = 1; m < 64; m <<= 1) {
      ull o = shfl_xor_u64(key, m);
      if (o > key) key = o;
    }
    if ((t & 63) == 0) warr[w] = key;
    __syncthreads();
    if (t == 0) {
      ull k = warr[0];
#pragma unroll
      for (int i = 1; i < 4; ++i)
        if (warr[i] > k) k = warr[i];
      winls = k;
      cand[b * CC + round] = (int)(k & 0xFFFFFFFFull);
    }
    __syncthreads();
    int wj = (int)(winls & 0xFFFFFFFFull);
    if (t == (wj & 255)) v[wj >> 8] = NEG_BIG;
  }
}

// ---------------------------------------------------------------------------
// Kernel 4: fp32 rescue partial maxes. Q rows for candidates are wave-uniform
// -> read via scalar pipe directly from global (no LDS).
// ---------------------------------------------------------------------------
__global__ __launch_bounds__(256) void rescue_kernel(const float* __restrict__ Q,
                                                     const float* __restrict__ K,
                                                     const int* __restrict__ idx,
                                                     const int* __restrict__ cand,
                                                     float* __restrict__ Mpart) {
  int seg = blockIdx.x, b = blockIdx.y, t = threadIdx.x;
  int w = t >> 6;
  __shared__ float redm[CC][4];

  int key = idx[seg * 256 + t];
  float4 kr[16];
  const float4* Krow = (const float4*)(K + ((size_t)b * LL + key) * DD);
#pragma unroll
  for (int i = 0; i < 16; ++i) kr[i] = Krow[i];

#pragma unroll 2
  for (int u = 0; u < CC; ++u) {
    int ci = cand[b * CC + u];  // uniform -> scalar load
    const float4* qp = (const float4*)(Q + ((size_t)b * LL + ci) * DD);
    float d = 0.f;
#pragma unroll
    for (int i = 0; i < 16; ++i) {
      float4 qv = qp[i];  // uniform -> s_load_dwordx4
      d = fmaf(qv.x, kr[i].x, d);
      d = fmaf(qv.y, kr[i].y, d);
      d = fmaf(qv.z, kr[i].z, d);
      d = fmaf(qv.w, kr[i].w, d);
    }
#pragma unroll
    for (int m = 1; m < 64; m <<= 1) d = fmaxf(d, __shfl_xor(d, m));
    if ((t & 63) == 0) redm[u][w] = d;
  }
  __syncthreads();
  if (t < CC) {
    float m = fmaxf(fmaxf(redm[t][0], redm[t][1]), fmaxf(redm[t][2], redm[t][3]));
    Mpart[((size_t)b * CC + t) * 8 + seg] = m;
  }
}

// ---------------------------------------------------------------------------
// Kernel 5: exact fp32 M for candidates; top-40 via rank-by-counting (O(1)
// rounds). Keys are distinct u64 (value | 2047-ci) -> ranks are a permutation;
// ordering matches lax.top_k (desc value, ties -> lowest index).
// ---------------------------------------------------------------------------
__global__ __launch_bounds__(64) void select_kernel(const float* __restrict__ Q,
                                                    const float* __restrict__ Kpart,
                                                    const int* __restrict__ cand,
                                                    const float* __restrict__ Mpart,
                                                    int* __restrict__ topi) {
  int b = blockIdx.x, t = threadIdx.x;
  __shared__ float KsumS[64];
  __shared__ ull keys[CC];
  {
    float s = 0.f;
#pragma unroll
    for (int p = 0; p < 16; ++p) s += Kpart[(b * 16 + p) * 64 + t];
    KsumS[t] = s;
  }
  __syncthreads();
  int ci = cand[b * CC + t];
  float m = NEG_BIG;
#pragma unroll
  for (int s = 0; s < 8; ++s) m = fmaxf(m, Mpart[((size_t)b * CC + t) * 8 + s]);
  const float4* Qr = (const float4*)(Q + ((size_t)b * LL + ci) * DD);
  float s = 0.f;
#pragma unroll
  for (int i = 0; i < 16; ++i) {
    float4 qv = Qr[i];
    s += qv.x * KsumS[4 * i] + qv.y * KsumS[4 * i + 1] + qv.z * KsumS[4 * i + 2] +
         qv.w * KsumS[4 * i + 3];
  }
  float Mf = m - s * (1.0f / (float)LL);
  ull key = ((ull)fsort(Mf) << 32) | (ull)(uint)(2047 - ci);
  keys[t] = key;
  __syncthreads();
  int rank = 0;
#pragma unroll 8
  for (int j = 0; j < CC; ++j) rank += (keys[j] > key) ? 1 : 0;
  if (rank < UU) topi[b * UU + rank] = ci;
}

// ---------------------------------------------------------------------------
// Kernel 6: FUSED epilogue per (seg, b): scores (exact fp32 output) + exp (no
// max subtraction; |s|<~6 so safe) + per-seg exp-sum + partial P.V.
// Q rows wave-uniform -> scalar loads, no Q LDS. pT stride 42 -> b64 LDS ops.
// ---------------------------------------------------------------------------
__global__ __launch_bounds__(256, 1) void fused_epilogue_kernel(
    const float* __restrict__ Q, const float* __restrict__ K,
    const float* __restrict__ V, const int* __restrict__ topi,
    float* __restrict__ scores, float* __restrict__ Opart,
    float* __restrict__ lpart) {
  int seg = blockIdx.x, b = blockIdx.y, t = threadIdx.x;
  __shared__ float pT[256 * PSTR];   // 43008 B; reused as red[4][40][64]
  __shared__ float lw[4][UU];        // 640 B

  // ---- Phase A: scores + exp (thread t owns key k) ----
  int k = seg * 256 + t;
  float4 kr[16];
  const float4* Krow = (const float4*)(K + ((size_t)b * LL + k) * DD);
#pragma unroll
  for (int i = 0; i < 16; ++i) kr[i] = Krow[i];

  float p[UU];
#pragma unroll 4
  for (int u = 0; u < UU; ++u) {
    int ci = topi[b * UU + u];  // uniform -> scalar load
    const float4* qp = (const float4*)(Q + ((size_t)b * LL + ci) * DD);
    float s = 0.f;
#pragma unroll
    for (int i = 0; i < 16; ++i) {
      float4 qv = qp[i];  // uniform -> s_load_dwordx4
      s += qv.x * kr[i].x + qv.y * kr[i].y + qv.z * kr[i].z + qv.w * kr[i].w;
    }
    s *= 0.125f;
    scores[((size_t)(b * UU + u)) * LL + k] = s;
    p[u] = __expf(s);
  }

  // ---- Phase B: per-seg exp-sums + transpose p into LDS (b64 writes) ----
  int w = t >> 6;
#pragma unroll
  for (int u = 0; u < UU; ++u) {
    float ls = p[u];
#pragma unroll
    for (int off = 32; off > 0; off >>= 1) ls += __shfl_xor(ls, off);
    if ((t & 63) == 0) lw[w][u] = ls;
  }
#pragma unroll
  for (int u = 0; u < UU; u += 2) {
    *(float2*)&pT[t * PSTR + u] = make_float2(p[u], p[u + 1]);
  }
  __syncthreads();
  if (t < UU) lpart[(size_t)(b * NSEG + seg) * UU + t] =
      lw[0][t] + lw[1][t] + lw[2][t] + lw[3][t];

  // ---- Phase C: partial P.V ----
  // thread (d4 = t&15, c = t>>4): u-group ug = c&3 (10 u), k-quarter kq = c>>2.
  int d4 = t & 15, c = t >> 4;
  int ug = c & 3, kq = c >> 2;
  int u0 = ug * 10;
  float4 acc[10];
#pragma unroll
  for (int j = 0; j < 10; ++j) acc[j] = (float4){0.f, 0.f, 0.f, 0.f};
  const float* Vb = V + ((size_t)b * LL + seg * 256 + kq * 64) * DD;
  for (int kk = 0; kk < 64; ++kk) {
    float4 v4 = *(const float4*)(Vb + (size_t)kk * DD + 4 * d4);
    const float* prow = &pT[(kq * 64 + kk) * PSTR + u0];
    float2 pj[5];
#pragma unroll
    for (int h = 0; h < 5; ++h) pj[h] = *(const float2*)&prow[2 * h];  // b64 reads
#pragma unroll
    for (int h = 0; h < 5; ++h) {
      float pa = pj[h].x, pb = pj[h].y;
      acc[2 * h].x += pa * v4.x; acc[2 * h].y += pa * v4.y;
      acc[2 * h].z += pa * v4.z; acc[2 * h].w += pa * v4.w;
      acc[2 * h + 1].x += pb * v4.x; acc[2 * h + 1].y += pb * v4.y;
      acc[2 * h + 1].z += pb * v4.z; acc[2 * h + 1].w += pb * v4.w;
    }
  }
  __syncthreads();  // all pT reads done before aliasing as red
  float* red = pT;  // red[kq][u][d] = red[(kq*40+u)*64 + d], 40960 B
#pragma unroll
  for (int j = 0; j < 10; ++j)
    *(float4*)&red[(kq * 40 + u0 + j) * 64 + 4 * d4] = acc[j];
  __syncthreads();
  for (int li = t; li < UU * DD; li += 256) {
    int u = li >> 6, d = li & 63;
    float s = red[(0 * 40 + u) * 64 + d] + red[(1 * 40 + u) * 64 + d] +
              red[(2 * 40 + u) * 64 + d] + red[(3 * 40 + u) * 64 + d];
    Opart[((size_t)(b * NSEG + seg) * UU + u) * DD + d] = s;
  }
}

// ---------------------------------------------------------------------------
// Kernel 7: combine segments: out = (sum_s Opart) / (sum_s lpart).
// ---------------------------------------------------------------------------
__global__ __launch_bounds__(256) void combine_kernel(const float* __restrict__ Opart,
                                                      const float* __restrict__ lpart,
                                                      float* __restrict__ out) {
  int b = blockIdx.x, t = threadIdx.x;
  __shared__ float Linv[UU];
  if (t < UU) {
    float Lsum = 0.f;
#pragma unroll
    for (int s = 0; s < NSEG; ++s) Lsum += lpart[(size_t)(b * NSEG + s) * UU + t];
    Linv[t] = 1.0f / Lsum;
  }
  __syncthreads();
  for (int li = t; li < UU * DD; li += 256) {
    int u = li >> 6, d = li & 63;
    float O = 0.f;
#pragma unroll
    for (int s = 0; s < NSEG; ++s)
      O += Opart[((size_t)(b * NSEG + s) * UU + u) * DD + d];
    out[((size_t)b * UU + u) * DD + d] = O * Linv[u];
  }
}

// ========================= fp32 fallback (round-2 path) ====================
__global__ __launch_bounds__(256) void m_kernel(const float* __restrict__ Q,
                                                const float* __restrict__ K,
                                                const int* __restrict__ idx,
                                                const float* __restrict__ Kpart,
                                                float* __restrict__ M) {
  __shared__ float Qs[128][68];
  __shared__ float Ks[128][68];
  __shared__ float KsumS[64];
  __shared__ float red[128][17];
  int b = blockIdx.y, q0 = blockIdx.x * 128, tid = threadIdx.x;
  int tx = tid & 15, ty = tid >> 4;
  if (tid < 64) {
    float s = 0.f;
#pragma unroll
    for (int p = 0; p < 16; ++p) s += Kpart[(b * 16 + p) * 64 + tid];
    KsumS[tid] = s;
  }
#pragma unroll
  for (int it = 0; it < 8; ++it) {
    int li = it * 256 + tid;
    int q = li >> 4, dd = (li & 15) << 2;
    *(float4*)&Qs[q][dd] = *(const float4*)(Q + ((size_t)b * LL + q0 + q) * DD + dd);
  }
  float mx[8];
#pragma unroll
  for (int i = 0; i < 8; ++i) mx[i] = NEG_BIG;
  for (int c = 0; c < LL / 128; ++c) {
    __syncthreads();
#pragma unroll
    for (int it = 0; it < 8; ++it) {
      int li = it * 256 + tid;
      int kk = li >> 4, dd = (li & 15) << 2;
      int gk = idx[c * 128 + kk];
      *(float4*)&Ks[kk][dd] = *(const float4*)(K + ((size_t)b * LL + gk) * DD + dd);
    }
    __syncthreads();
    float acc[8][8];
#pragma unroll
    for (int i = 0; i < 8; ++i)
#pragma unroll
      for (int j = 0; j < 8; ++j) acc[i][j] = 0.f;
#pragma unroll 2
    for (int dd = 0; dd < 64; dd += 4) {
      float4 qf[8];
#pragma unroll
      for (int i = 0; i < 8; ++i) qf[i] = *(const float4*)&Qs[tx + 16 * i][dd];
#pragma unroll
      for (int j = 0; j < 8; ++j) {
        float4 kf = *(const float4*)&Ks[ty + 16 * j][dd];
#pragma unroll
        for (int i = 0; i < 8; ++i)
          acc[i][j] += qf[i].x * kf.x + qf[i].y * kf.y + qf[i].z * kf.z + qf[i].w * kf.w;
      }
    }
#pragma unroll
    for (int i = 0; i < 8; ++i) {
      float m01 = fmaxf(fmaxf(acc[i][0], acc[i][1]), fmaxf(acc[i][2], acc[i][3]));
      float m23 = fmaxf(fmaxf(acc[i][4], acc[i][5]), fmaxf(acc[i][6], acc[i][7]));
      mx[i] = fmaxf(mx[i], fmaxf(m01, m23));
    }
  }
  __syncthreads();
#pragma unroll
  for (int i = 0; i < 8; ++i) red[tx + 16 * i][ty] = mx[i];
  __syncthreads();
  if (tid < 128) {
    float m = red[tid][0];
#pragma unroll
    for (int tt = 1; tt < 16; ++tt) m = fmaxf(m, red[tid][tt]);
    float s = 0.f;
#pragma unroll 16
    for (int d = 0; d < 64; ++d) s += Qs[tid][d] * KsumS[d];
    M[b * LL + q0 + tid] = m - s * (1.0f / (float)LL);
  }
}

__global__ __launch_bounds__(256) void topk_kernel(const float* __restrict__ M,
                                                   int* __restrict__ topi) {
  int b = blockIdx.x, tid = threadIdx.x;
  __shared__ float mv[LL];
  __shared__ float wv[4];
  __shared__ int wi[4];
  for (int j = tid; j < LL; j += 256) mv[j] = M[b * LL + j];
  __syncthreads();
  for (int t = 0; t < UU; ++t) {
    float bv = NEG_BIG;
    int bi = 0x7fffffff;
    for (int j = tid; j < LL; j += 256) {
      float v = mv[j];
      if (v > bv) { bv = v; bi = j; }
    }
#pragma unroll
    for (int off = 32; off > 0; off >>= 1) {
      float ov = __shfl_down(bv, off);
      int oi = __shfl_down(bi, off);
      if (ov > bv || (ov == bv && oi < bi)) { bv = ov; bi = oi; }
    }
    if ((tid & 63) == 0) { wv[tid >> 6] = bv; wi[tid >> 6] = bi; }
    __syncthreads();
    if (tid == 0) {
#pragma unroll
      for (int w = 1; w < 4; ++w)
        if (wv[w] > bv || (wv[w] == bv && wi[w] < bi)) { bv = wv[w]; bi = wi[w]; }
      topi[b * UU + t] = bi;
      mv[bi] = NEG_BIG;
    }
    __syncthreads();
  }
}

__global__ __launch_bounds__(256) void scores_kernel(const float* __restrict__ Q,
                                                     const float* __restrict__ K,
                                                     const int* __restrict__ topi,
                                                     float* __restrict__ scores) {
  int b = blockIdx.y;
  int k = blockIdx.x * 256 + threadIdx.x;
  __shared__ float Qr[UU][DD];
  for (int li = threadIdx.x; li < UU * DD; li += 256) {
    int u = li >> 6, d = li & 63;
    Qr[u][d] = Q[((size_t)b * LL + topi[b * UU + u]) * DD + d];
  }
  __syncthreads();
  float4 kr[16];
  const float4* Krow = (const float4*)(K + ((size_t)b * LL + k) * DD);
#pragma unroll
  for (int i = 0; i < 16; ++i) kr[i] = Krow[i];
  for (int u = 0; u < UU; ++u) {
    float s = 0.f;
#pragma unroll
    for (int i = 0; i < 16; ++i) {
      float4 qv = *(const float4*)&Qr[u][i << 2];
      s += qv.x * kr[i].x + qv.y * kr[i].y + qv.z * kr[i].z + qv.w * kr[i].w;
    }
    scores[((size_t)(b * UU + u)) * LL + k] = s * 0.125f;
  }
}

__global__ __launch_bounds__(256) void softmax_pv_kernel(const float* __restrict__ scores,
                                                         const float* __restrict__ V,
                                                         float* __restrict__ out) {
  int b = blockIdx.y;
  int u0 = blockIdx.x * 4;
  int tid = threadIdx.x;
  __shared__ float p[4][LL];
  __shared__ float wred[4];
  __shared__ float inv_s[4];
  __shared__ float r2[256];
#pragma unroll
  for (int uu = 0; uu < 4; ++uu) {
    const float* srow = scores + ((size_t)(b * UU + u0 + uu)) * LL;
    float m = NEG_BIG;
    for (int j = tid; j < LL; j += 256) m = fmaxf(m, srow[j]);
#pragma unroll
    for (int off = 32; off > 0; off >>= 1) m = fmaxf(m, __shfl_down(m, off));
    if ((tid & 63) == 0) wred[tid >> 6] = m;
    __syncthreads();
    float smax = fmaxf(fmaxf(wred[0], wred[1]), fmaxf(wred[2], wred[3]));
    __syncthreads();
    float ls = 0.f;
    for (int j = tid; j < LL; j += 256) {
      float e = __expf(srow[j] - smax);
      p[uu][j] = e;
      ls += e;
    }
#pragma unroll
    for (int off = 32; off > 0; off >>= 1) ls += __shfl_down(ls, off);
    if ((tid & 63) == 0) wred[tid >> 6] = ls;
    __syncthreads();
    if (tid == 0) inv_s[uu] = 1.0f / (wred[0] + wred[1] + wred[2] + wred[3]);
    __syncthreads();
  }
  int d = tid & 63, c = tid >> 6;
  float acc[4] = {0.f, 0.f, 0.f, 0.f};
  const float* Vb = V + (size_t)b * LL * DD;
  int k0 = c * (LL / 4), k1 = k0 + (LL / 4);
  for (int k = k0; k < k1; ++k) {
    float v = Vb[(size_t)k * DD + d];
#pragma unroll
    for (int uu = 0; uu < 4; ++uu) acc[uu] += p[uu][k] * v;
  }
#pragma unroll
  for (int uu = 0; uu < 4; ++uu) {
    r2[tid] = acc[uu];
    __syncthreads();
    if (c == 0) {
      out[((size_t)(b * UU) + u0 + uu) * DD + d] =
          (r2[d] + r2[64 + d] + r2[128 + d] + r2[192 + d]) * inv_s[uu];
    }
    __syncthreads();
  }
}

// ---------------------------------------------------------------------------
extern "C" void kernel_launch(void* const* d_in, const int* in_sizes, int n_in,
                              void* d_out, int out_size, void* d_ws, size_t ws_size,
                              hipStream_t stream) {
  (void)in_sizes; (void)n_in; (void)out_size;
  const float* Q = (const float*)d_in[0];
  const float* K = (const float*)d_in[1];
  const float* V = (const float*)d_in[2];
  const int* idx = (const int*)d_in[3];

  float* out = (float*)d_out;
  float* scores = out + (size_t)BB * UU * DD;

  // fast-path workspace layout (~3.1 MB)
  const size_t kpart_off = 0;
  const size_t mb_off = kpart_off + (size_t)BB * 16 * DD * sizeof(float);
  const size_t mpart_off = mb_off + (size_t)BB * LL * sizeof(float);
  const size_t cand_off = mpart_off + (size_t)BB * CC * NSEG * sizeof(float);
  const size_t topi_off = cand_off + (size_t)BB * CC * sizeof(int);
  const size_t opart_off = topi_off + (size_t)BB * UU * sizeof(int);
  const size_t lpart_off = opart_off + (size_t)BB * NSEG * UU * DD * sizeof(float);
  const size_t need = lpart_off + (size_t)BB * NSEG * UU * sizeof(float);

  char* ws = (char*)d_ws;
  if (ws_size >= need) {
    float* Kpart = (float*)(ws + kpart_off);
    float* Mb = (float*)(ws + mb_off);
    float* Mpart = (float*)(ws + mpart_off);
    int* cand = (int*)(ws + cand_off);
    int* topi = (int*)(ws + topi_off);
    float* Opart = (float*)(ws + opart_off);
    float* lpart = (float*)(ws + lpart_off);

    ksum_kernel<<<dim3(16, BB), 256, 0, stream>>>(K, idx, Kpart);
    mfma_m_kernel<<<dim3(LL / 128, BB), 256, 0, stream>>>(Q, K, idx, Kpart, Mb);
    cand_kernel<<<BB, 256, 0, stream>>>(Mb, cand);
    rescue_kernel<<<dim3(NSEG, BB), 256, 0, stream>>>(Q, K, idx, cand, Mpart);
    select_kernel<<<BB, 64, 0, stream>>>(Q, Kpart, cand, Mpart, topi);
    fused_epilogue_kernel<<<dim3(NSEG, BB), 256, 0, stream>>>(Q, K, V, topi, scores,
                                                              Opart, lpart);
    combine_kernel<<<BB, 256, 0, stream>>>(Opart, lpart, out);
  } else {
    // fp32 fallback (round-2 path), aliasing dead d_out regions
    size_t need2 =
        (size_t)(BB * LL + BB * 16 * DD) * sizeof(float) + (size_t)(BB * UU) * sizeof(int);
    float* M;
    float* Kpart;
    int* topi;
    if (ws_size >= need2) {
      M = (float*)d_ws;
      Kpart = M + BB * LL;
      topi = (int*)(Kpart + BB * 16 * DD);
    } else {
      M = scores;
      Kpart = scores + BB * LL;
      topi = (int*)out;
    }
    ksum_kernel<<<dim3(16, BB), 256, 0, stream>>>(K, idx, Kpart);
    m_kernel<<<dim3(LL / 128, BB), 256, 0, stream>>>(Q, K, idx, Kpart, M);
    topk_kernel<<<BB, 256, 0, stream>>>(M, topi);
    scores_kernel<<<dim3(LL / 256, BB), 256, 0, stream>>>(Q, K, topi, scores);
    softmax_pv_kernel<<<dim3(UU / 4, BB), 256, 0, stream>>>(scores, V, out);
  }
}

// Round 6
// 252.437 us; speedup vs baseline: 1.2385x; 1.2385x over previous
//
#include <hip/hip_runtime.h>
#include <math.h>

#define BB 32
#define LL 2048
#define DD 64
#define UU 40
#define CC 64            // bf16-phase candidates per batch
#define FSEG 16          // epilogue/rescue key segments (128 keys each)
#define PSTR 42          // pT row stride (floats); even -> 8B-aligned b64 ops
#define NEG_BIG (-3.0e38f)

typedef __attribute__((ext_vector_type(8))) short short8;
typedef __attribute__((ext_vector_type(4))) float f32x4;
typedef unsigned long long ull;
typedef unsigned int uint;
typedef unsigned short ushort_t;

__device__ __forceinline__ unsigned short f2bf(float f) {
  uint u = __float_as_uint(f);
  u += 0x7FFFu + ((u >> 16) & 1u);   // RNE
  return (unsigned short)(u >> 16);
}
__device__ __forceinline__ uint fsort(float f) {
  uint u = __float_as_uint(f);
  return (u & 0x80000000u) ? ~u : (u | 0x80000000u);  // monotonic map
}
__device__ __forceinline__ ull shfl_xor_u64(ull x, int m) {
  uint lo = (uint)x, hi = (uint)(x >> 32);
  lo = __shfl_xor(lo, m);
  hi = __shfl_xor(hi, m);
  return ((ull)hi << 32) | lo;
}
__device__ __forceinline__ int4 pack_bf16x8(float4 a, float4 c4) {
  int4 o;
  o.x = (int)(f2bf(a.x) | ((uint)f2bf(a.y) << 16));
  o.y = (int)(f2bf(a.z) | ((uint)f2bf(a.w) << 16));
  o.z = (int)(f2bf(c4.x) | ((uint)f2bf(c4.y) << 16));
  o.w = (int)(f2bf(c4.z) | ((uint)f2bf(c4.w) << 16));
  return o;
}

// ---------------------------------------------------------------------------
// Kernel 1: gathered K -> bf16 (Kg) + partial Ksum (Kpart) in one pass.
// ---------------------------------------------------------------------------
__global__ __launch_bounds__(256) void prep_ksum_kernel(const float* __restrict__ K,
                                                        const int* __restrict__ idx,
                                                        ushort_t* __restrict__ Kg,
                                                        float* __restrict__ Kpart) {
  int p = blockIdx.x, b = blockIdx.y, t = threadIdx.x;
  int g = t & 7;  // 16B group = 8 elements
  float4 sa = {0.f, 0.f, 0.f, 0.f}, sb = {0.f, 0.f, 0.f, 0.f};
#pragma unroll
  for (int it = 0; it < 4; ++it) {
    int r = p * 128 + it * 32 + (t >> 3);
    int gk = idx[r];
    const float* src = K + ((size_t)b * LL + gk) * DD + g * 8;
    float4 a = *(const float4*)src;
    float4 c4 = *(const float4*)(src + 4);
    sa.x += a.x; sa.y += a.y; sa.z += a.z; sa.w += a.w;
    sb.x += c4.x; sb.y += c4.y; sb.z += c4.z; sb.w += c4.w;
    *(int4*)(Kg + ((size_t)b * LL + r) * DD + g * 8) = pack_bf16x8(a, c4);
  }
  __shared__ float red[32][64];
  int rt = t >> 3;
  *(float4*)&red[rt][g * 8] = sa;
  *(float4*)&red[rt][g * 8 + 4] = sb;
  __syncthreads();
  if (t < 64) {
    float s = 0.f;
#pragma unroll
    for (int r = 0; r < 32; ++r) s += red[r][t];
    Kpart[(b * 16 + p) * 64 + t] = s;
  }
}

// ---------------------------------------------------------------------------
// Kernel 2: bf16 MFMA M-scores. Q converted inline during staging; K from Kg.
// Mb[b][q] = max_j(Q.K_sample[j]) - (Q.Ksum)/L.
// ---------------------------------------------------------------------------
__global__ __launch_bounds__(256) void mfma_m_kernel(const float* __restrict__ Q,
                                                     const ushort_t* __restrict__ Kg,
                                                     const float* __restrict__ Kpart,
                                                     float* __restrict__ Mb) {
  __shared__ __align__(16) ushort_t Qs[128 * 64];  // 16 KB, swizzled
  __shared__ __align__(16) ushort_t Ks[128 * 64];  // 16 KB, swizzled
  __shared__ float Mmax[2][128];
  __shared__ float KsumS[64];

  int b = blockIdx.y, q0 = blockIdx.x * 128;
  int t = threadIdx.x;
  int w = t >> 6, L = t & 63;

  if (t < 64) {
    float s = 0.f;
#pragma unroll
    for (int p = 0; p < 16; ++p) s += Kpart[(b * 16 + p) * 64 + t];
    KsumS[t] = s;
  }

  // stage Q tile once: read fp32, convert to bf16, swizzled store
  {
    int g = t & 7;
#pragma unroll
    for (int it = 0; it < 4; ++it) {
      int r = it * 32 + (t >> 3);
      const float* src = Q + ((size_t)b * LL + q0 + r) * DD + g * 8;
      float4 a = *(const float4*)src;
      float4 c4 = *(const float4*)(src + 4);
      *(int4*)&Qs[r * 64 + 8 * (g ^ (r & 7))] = pack_bf16x8(a, c4);
    }
  }

  f32x4 mx[4];
#pragma unroll
  for (int i = 0; i < 4; ++i) mx[i] = (f32x4){NEG_BIG, NEG_BIG, NEG_BIG, NEG_BIG};

  const int waveQ = 64 * (w & 1);
  const int waveK = 64 * (w >> 1);
  const int lm = L & 15;
  const int lq = L >> 4;

  for (int c = 0; c < LL / 128; ++c) {
    __syncthreads();
    {
      int g = t & 7;
#pragma unroll
      for (int it = 0; it < 4; ++it) {
        int r = it * 32 + (t >> 3);
        int4 v = *(const int4*)(Kg + ((size_t)b * LL + c * 128 + r) * DD + g * 8);
        *(int4*)&Ks[r * 64 + 8 * (g ^ (r & 7))] = v;
      }
    }
    __syncthreads();

    f32x4 acc[4][4];
#pragma unroll
    for (int i = 0; i < 4; ++i)
#pragma unroll
      for (int j = 0; j < 4; ++j) acc[i][j] = (f32x4){0.f, 0.f, 0.f, 0.f};

#pragma unroll
    for (int s = 0; s < 2; ++s) {
      int g = 4 * s + lq;
      short8 A[4];
#pragma unroll
      for (int qt = 0; qt < 4; ++qt) {
        int r = waveQ + 16 * qt + lm;
        A[qt] = *(const short8*)&Qs[r * 64 + 8 * (g ^ (r & 7))];
      }
#pragma unroll
      for (int kt = 0; kt < 4; ++kt) {
        int rB = waveK + 16 * kt + lm;
        short8 Bf = *(const short8*)&Ks[rB * 64 + 8 * (g ^ (rB & 7))];
#pragma unroll
        for (int qt = 0; qt < 4; ++qt) {
          acc[qt][kt] = __builtin_amdgcn_mfma_f32_16x16x32_bf16(A[qt], Bf, acc[qt][kt], 0, 0, 0);
        }
      }
    }
#pragma unroll
    for (int qt = 0; qt < 4; ++qt)
#pragma unroll
      for (int kt = 0; kt < 4; ++kt) {
#pragma unroll
        for (int r4 = 0; r4 < 4; ++r4) mx[qt][r4] = fmaxf(mx[qt][r4], acc[qt][kt][r4]);
      }
  }

#pragma unroll
  for (int qt = 0; qt < 4; ++qt) {
#pragma unroll
    for (int r4 = 0; r4 < 4; ++r4) {
      float v = mx[qt][r4];
      v = fmaxf(v, __shfl_xor(v, 1));
      v = fmaxf(v, __shfl_xor(v, 2));
      v = fmaxf(v, __shfl_xor(v, 4));
      v = fmaxf(v, __shfl_xor(v, 8));
      mx[qt][r4] = v;
    }
  }
  if (lm < 4) {
    int qt = lm;
#pragma unroll
    for (int r4 = 0; r4 < 4; ++r4) {
      Mmax[w >> 1][waveQ + 16 * qt + 4 * lq + r4] = mx[qt][r4];
    }
  }
  __syncthreads();

  if (t < 128) {
    float m = fmaxf(Mmax[0][t], Mmax[1][t]);
    const float4* Qr = (const float4*)(Q + ((size_t)b * LL + q0 + t) * DD);
    float s = 0.f;
#pragma unroll
    for (int i = 0; i < 16; ++i) {
      float4 qv = Qr[i];
      s += qv.x * KsumS[4 * i] + qv.y * KsumS[4 * i + 1] + qv.z * KsumS[4 * i + 2] +
           qv.w * KsumS[4 * i + 3];
    }
    Mb[b * LL + q0 + t] = m - s * (1.0f / (float)LL);
  }
}

// ---------------------------------------------------------------------------
// Kernel 3: per-batch top-64 candidate set by Mb (set only; any order).
// ---------------------------------------------------------------------------
__global__ __launch_bounds__(256) void cand_kernel(const float* __restrict__ Mb,
                                                   int* __restrict__ cand) {
  int b = blockIdx.x, t = threadIdx.x;
  int w = t >> 6;
  float v[8];
#pragma unroll
  for (int i = 0; i < 8; ++i) v[i] = Mb[b * LL + t + 256 * i];
  __shared__ ull warr[4];
  __shared__ ull winls;
  for (int round = 0; round < CC; ++round) {
    float bv = v[0];
    int bi = 0;
#pragma unroll
    for (int i = 1; i < 8; ++i)
      if (v[i] > bv) { bv = v[i]; bi = i; }
    ull key = ((ull)fsort(bv) << 32) | (ull)(uint)(t + 256 * bi);
#pragma unroll
    for (int m = 1; m < 64; m <<= 1) {
      ull o = shfl_xor_u64(key, m);
      if (o > key) key = o;
    }
    if ((t & 63) == 0) warr[w] = key;
    __syncthreads();
    if (t == 0) {
      ull k = warr[0];
#pragma unroll
      for (int i = 1; i < 4; ++i)
        if (warr[i] > k) k = warr[i];
      winls = k;
      cand[b * CC + round] = (int)(k & 0xFFFFFFFFull);
    }
    __syncthreads();
    int wj = (int)(winls & 0xFFFFFFFFull);
    if (t == (wj & 255)) v[wj >> 8] = NEG_BIG;
  }
}

// ---------------------------------------------------------------------------
// Kernel 4: fp32 rescue partial maxes over candidate queries.
// 16 segments x 128 keys; thread (kl = t&127, uh = t>>7) covers 32 u's.
// Q rows wave-uniform -> scalar loads.
// ---------------------------------------------------------------------------
__global__ __launch_bounds__(256) void rescue_kernel(const float* __restrict__ Q,
                                                     const float* __restrict__ K,
                                                     const int* __restrict__ idx,
                                                     const int* __restrict__ cand,
                                                     float* __restrict__ Mpart) {
  int seg = blockIdx.x, b = blockIdx.y, t = threadIdx.x;
  int w = t >> 6;        // wave 0..3
  int kl = t & 127;      // key lane
  int uh = t >> 7;       // u half (uniform per wave)
  __shared__ float redm[CC][4];

  int key = idx[seg * 128 + kl];
  float4 kr[16];
  const float4* Krow = (const float4*)(K + ((size_t)b * LL + key) * DD);
#pragma unroll
  for (int i = 0; i < 16; ++i) kr[i] = Krow[i];

#pragma unroll 2
  for (int uu = 0; uu < 32; ++uu) {
    int u = uh * 32 + uu;
    int ci = cand[b * CC + u];  // uniform -> scalar load
    const float4* qp = (const float4*)(Q + ((size_t)b * LL + ci) * DD);
    float d = 0.f;
#pragma unroll
    for (int i = 0; i < 16; ++i) {
      float4 qv = qp[i];  // uniform -> s_load
      d = fmaf(qv.x, kr[i].x, d);
      d = fmaf(qv.y, kr[i].y, d);
      d = fmaf(qv.z, kr[i].z, d);
      d = fmaf(qv.w, kr[i].w, d);
    }
#pragma unroll
    for (int m = 1; m < 64; m <<= 1) d = fmaxf(d, __shfl_xor(d, m));
    if ((t & 63) == 0) redm[u][w] = d;
  }
  __syncthreads();
  if (t < CC) {
    int u = t;
    float m = (u < 32) ? fmaxf(redm[u][0], redm[u][1])
                       : fmaxf(redm[u][2], redm[u][3]);
    Mpart[((size_t)b * CC + u) * FSEG + seg] = m;
  }
}

// ---------------------------------------------------------------------------
// Kernel 5: exact fp32 M for candidates; top-40 via rank-by-counting.
// Keys distinct (value | 2047-ci) -> rank permutation == lax.top_k order.
// ---------------------------------------------------------------------------
__global__ __launch_bounds__(64) void select_kernel(const float* __restrict__ Q,
                                                    const float* __restrict__ Kpart,
                                                    const int* __restrict__ cand,
                                                    const float* __restrict__ Mpart,
                                                    int* __restrict__ topi) {
  int b = blockIdx.x, t = threadIdx.x;
  __shared__ float KsumS[64];
  __shared__ ull keys[CC];
  {
    float s = 0.f;
#pragma unroll
    for (int p = 0; p < 16; ++p) s += Kpart[(b * 16 + p) * 64 + t];
    KsumS[t] = s;
  }
  __syncthreads();
  int ci = cand[b * CC + t];
  float m = NEG_BIG;
#pragma unroll
  for (int s = 0; s < FSEG; ++s) m = fmaxf(m, Mpart[((size_t)b * CC + t) * FSEG + s]);
  const float4* Qr = (const float4*)(Q + ((size_t)b * LL + ci) * DD);
  float s = 0.f;
#pragma unroll
  for (int i = 0; i < 16; ++i) {
    float4 qv = Qr[i];
    s += qv.x * KsumS[4 * i] + qv.y * KsumS[4 * i + 1] + qv.z * KsumS[4 * i + 2] +
         qv.w * KsumS[4 * i + 3];
  }
  float Mf = m - s * (1.0f / (float)LL);
  ull key = ((ull)fsort(Mf) << 32) | (ull)(uint)(2047 - ci);
  keys[t] = key;
  __syncthreads();
  int rank = 0;
#pragma unroll 8
  for (int j = 0; j < CC; ++j) rank += (keys[j] > key) ? 1 : 0;
  if (rank < UU) topi[b * UU + rank] = ci;
}

// ---------------------------------------------------------------------------
// Kernel 6: FUSED epilogue per (seg, b), 128 keys/seg: scores (exact fp32
// output) + exp (no max subtraction; |s|<~6 safe) + per-seg exp-sum +
// partial P.V. LDS Qc broadcast feed; thread (kl, uh) does 20 u's each.
// ---------------------------------------------------------------------------
__global__ __launch_bounds__(256, 2) void fused_epilogue_kernel(
    const float* __restrict__ Q, const float* __restrict__ K,
    const float* __restrict__ V, const int* __restrict__ topi,
    float* __restrict__ scores, float* __restrict__ Opart,
    float* __restrict__ lpart) {
  int seg = blockIdx.x, b = blockIdx.y, t = threadIdx.x;
  __shared__ int cidx[UU];
  __shared__ float Qc[UU][DD];       // 10240 B
  __shared__ float pT[128 * PSTR];   // 21504 B; aliased as red[2][40][64]
  __shared__ float lw[4][20];        // 320 B

  if (t < UU) cidx[t] = topi[b * UU + t];
  __syncthreads();
  for (int li = t; li < UU * 16; li += 256) {
    int u = li >> 4, g4 = li & 15;
    *(float4*)&Qc[u][4 * g4] =
        *(const float4*)(Q + ((size_t)b * LL + cidx[u]) * DD + 4 * g4);
  }
  __syncthreads();

  // ---- Phase A: scores + exp. thread (kl = t&127, uh = t>>7) ----
  int kl = t & 127, uh = t >> 7, w = t >> 6;
  int k = seg * 128 + kl;
  float4 kr[16];
  const float4* Krow = (const float4*)(K + ((size_t)b * LL + k) * DD);
#pragma unroll
  for (int i = 0; i < 16; ++i) kr[i] = Krow[i];

  float p[20];
#pragma unroll 4
  for (int j = 0; j < 20; ++j) {
    int u = uh * 20 + j;
    const float4* qp = (const float4*)&Qc[u][0];
    float s = 0.f;
#pragma unroll
    for (int i = 0; i < 16; ++i) {
      float4 qv = qp[i];  // broadcast LDS read
      s += qv.x * kr[i].x + qv.y * kr[i].y + qv.z * kr[i].z + qv.w * kr[i].w;
    }
    s *= 0.125f;
    scores[((size_t)(b * UU + u)) * LL + k] = s;
    p[j] = __expf(s);
  }

  // ---- Phase B: per-seg exp-sums (wave = 64 keys) + transpose p ----
#pragma unroll
  for (int j = 0; j < 20; ++j) {
    float ls = p[j];
#pragma unroll
    for (int off = 32; off > 0; off >>= 1) ls += __shfl_xor(ls, off);
    if ((t & 63) == 0) lw[w][j] = ls;
  }
#pragma unroll
  for (int j = 0; j < 20; j += 2) {
    *(float2*)&pT[kl * PSTR + uh * 20 + j] = make_float2(p[j], p[j + 1]);
  }
  __syncthreads();
  if (t < UU) {
    int u = t;
    float ls = (u < 20) ? (lw[0][u] + lw[1][u]) : (lw[2][u - 20] + lw[3][u - 20]);
    lpart[(size_t)(b * FSEG + seg) * UU + u] = ls;
  }

  // ---- Phase C: partial P.V ----
  // thread (d4 = t&15, c = t>>4): ug = c&7 -> 5 u's, kq = c>>3 -> 64 keys.
  int d4 = t & 15, c = t >> 4;
  int ug = c & 7, kq = c >> 3;
  int u0 = ug * 5;
  float4 acc[5];
#pragma unroll
  for (int j = 0; j < 5; ++j) acc[j] = (float4){0.f, 0.f, 0.f, 0.f};
  const float* Vb = V + ((size_t)b * LL + seg * 128 + kq * 64) * DD;
  for (int kk = 0; kk < 64; ++kk) {
    float4 v4 = *(const float4*)(Vb + (size_t)kk * DD + 4 * d4);
    const float* prow = &pT[(kq * 64 + kk) * PSTR + u0];
#pragma unroll
    for (int j = 0; j < 5; ++j) {
      float pj = prow[j];
      acc[j].x += pj * v4.x; acc[j].y += pj * v4.y;
      acc[j].z += pj * v4.z; acc[j].w += pj * v4.w;
    }
  }
  __syncthreads();  // all pT reads done before aliasing as red
  float* red = pT;  // red[kq][u][d] = red[(kq*40+u)*64 + d], 20480 B
#pragma unroll
  for (int j = 0; j < 5; ++j)
    *(float4*)&red[(kq * 40 + u0 + j) * 64 + 4 * d4] = acc[j];
  __syncthreads();
  for (int li = t; li < UU * DD; li += 256) {
    int u = li >> 6, d = li & 63;
    float s = red[u * 64 + d] + red[(40 + u) * 64 + d];
    Opart[((size_t)(b * FSEG + seg) * UU + u) * DD + d] = s;
  }
}

// ---------------------------------------------------------------------------
// Kernel 7: combine segments: out = (sum_s Opart) / (sum_s lpart).
// ---------------------------------------------------------------------------
__global__ __launch_bounds__(256) void combine_kernel(const float* __restrict__ Opart,
                                                      const float* __restrict__ lpart,
                                                      float* __restrict__ out) {
  int b = blockIdx.x, t = threadIdx.x;
  __shared__ float Linv[UU];
  if (t < UU) {
    float Lsum = 0.f;
#pragma unroll
    for (int s = 0; s < FSEG; ++s) Lsum += lpart[(size_t)(b * FSEG + s) * UU + t];
    Linv[t] = 1.0f / Lsum;
  }
  __syncthreads();
  for (int li = t; li < UU * DD; li += 256) {
    int u = li >> 6, d = li & 63;
    float O = 0.f;
#pragma unroll
    for (int s = 0; s < FSEG; ++s)
      O += Opart[((size_t)(b * FSEG + s) * UU + u) * DD + d];
    out[((size_t)b * UU + u) * DD + d] = O * Linv[u];
  }
}

// ========================= fp32 fallback (round-2 path) ====================
__global__ __launch_bounds__(256) void ksum_kernel(const float* __restrict__ K,
                                                   const int* __restrict__ idx,
                                                   float* __restrict__ Kpart) {
  int p = blockIdx.x, b = blockIdx.y, tid = threadIdx.x;
  int d = tid & 63, c = tid >> 6;
  const float* Kb = K + (size_t)b * LL * DD;
  float acc = 0.f;
  int j0 = p * 128 + c * 32;
#pragma unroll 4
  for (int t = 0; t < 32; ++t) acc += Kb[(size_t)idx[j0 + t] * DD + d];
  __shared__ float red[256];
  red[tid] = acc;
  __syncthreads();
  if (c == 0) Kpart[(b * 16 + p) * 64 + d] = red[d] + red[64 + d] + red[128 + d] + red[192 + d];
}

__global__ __launch_bounds__(256) void m_kernel(const float* __restrict__ Q,
                                                const float* __restrict__ K,
                                                const int* __restrict__ idx,
                                                const float* __restrict__ Kpart,
                                                float* __restrict__ M) {
  __shared__ float Qs[128][68];
  __shared__ float Ks[128][68];
  __shared__ float KsumS[64];
  __shared__ float red[128][17];
  int b = blockIdx.y, q0 = blockIdx.x * 128, tid = threadIdx.x;
  int tx = tid & 15, ty = tid >> 4;
  if (tid < 64) {
    float s = 0.f;
#pragma unroll
    for (int p = 0; p < 16; ++p) s += Kpart[(b * 16 + p) * 64 + tid];
    KsumS[tid] = s;
  }
#pragma unroll
  for (int it = 0; it < 8; ++it) {
    int li = it * 256 + tid;
    int q = li >> 4, dd = (li & 15) << 2;
    *(float4*)&Qs[q][dd] = *(const float4*)(Q + ((size_t)b * LL + q0 + q) * DD + dd);
  }
  float mx[8];
#pragma unroll
  for (int i = 0; i < 8; ++i) mx[i] = NEG_BIG;
  for (int c = 0; c < LL / 128; ++c) {
    __syncthreads();
#pragma unroll
    for (int it = 0; it < 8; ++it) {
      int li = it * 256 + tid;
      int kk = li >> 4, dd = (li & 15) << 2;
      int gk = idx[c * 128 + kk];
      *(float4*)&Ks[kk][dd] = *(const float4*)(K + ((size_t)b * LL + gk) * DD + dd);
    }
    __syncthreads();
    float acc[8][8];
#pragma unroll
    for (int i = 0; i < 8; ++i)
#pragma unroll
      for (int j = 0; j < 8; ++j) acc[i][j] = 0.f;
#pragma unroll 2
    for (int dd = 0; dd < 64; dd += 4) {
      float4 qf[8];
#pragma unroll
      for (int i = 0; i < 8; ++i) qf[i] = *(const float4*)&Qs[tx + 16 * i][dd];
#pragma unroll
      for (int j = 0; j < 8; ++j) {
        float4 kf = *(const float4*)&Ks[ty + 16 * j][dd];
#pragma unroll
        for (int i = 0; i < 8; ++i)
          acc[i][j] += qf[i].x * kf.x + qf[i].y * kf.y + qf[i].z * kf.z + qf[i].w * kf.w;
      }
    }
#pragma unroll
    for (int i = 0; i < 8; ++i) {
      float m01 = fmaxf(fmaxf(acc[i][0], acc[i][1]), fmaxf(acc[i][2], acc[i][3]));
      float m23 = fmaxf(fmaxf(acc[i][4], acc[i][5]), fmaxf(acc[i][6], acc[i][7]));
      mx[i] = fmaxf(mx[i], fmaxf(m01, m23));
    }
  }
  __syncthreads();
#pragma unroll
  for (int i = 0; i < 8; ++i) red[tx + 16 * i][ty] = mx[i];
  __syncthreads();
  if (tid < 128) {
    float m = red[tid][0];
#pragma unroll
    for (int tt = 1; tt < 16; ++tt) m = fmaxf(m, red[tid][tt]);
    float s = 0.f;
#pragma unroll 16
    for (int d = 0; d < 64; ++d) s += Qs[tid][d] * KsumS[d];
    M[b * LL + q0 + tid] = m - s * (1.0f / (float)LL);
  }
}

__global__ __launch_bounds__(256) void topk_kernel(const float* __restrict__ M,
                                                   int* __restrict__ topi) {
  int b = blockIdx.x, tid = threadIdx.x;
  __shared__ float mv[LL];
  __shared__ float wv[4];
  __shared__ int wi[4];
  for (int j = tid; j < LL; j += 256) mv[j] = M[b * LL + j];
  __syncthreads();
  for (int t = 0; t < UU; ++t) {
    float bv = NEG_BIG;
    int bi = 0x7fffffff;
    for (int j = tid; j < LL; j += 256) {
      float v = mv[j];
      if (v > bv) { bv = v; bi = j; }
    }
#pragma unroll
    for (int off = 32; off > 0; off >>= 1) {
      float ov = __shfl_down(bv, off);
      int oi = __shfl_down(bi, off);
      if (ov > bv || (ov == bv && oi < bi)) { bv = ov; bi = oi; }
    }
    if ((tid & 63) == 0) { wv[tid >> 6] = bv; wi[tid >> 6] = bi; }
    __syncthreads();
    if (tid == 0) {
#pragma unroll
      for (int w = 1; w < 4; ++w)
        if (wv[w] > bv || (wv[w] == bv && wi[w] < bi)) { bv = wv[w]; bi = wi[w]; }
      topi[b * UU + t] = bi;
      mv[bi] = NEG_BIG;
    }
    __syncthreads();
  }
}

__global__ __launch_bounds__(256) void scores_kernel(const float* __restrict__ Q,
                                                     const float* __restrict__ K,
                                                     const int* __restrict__ topi,
                                                     float* __restrict__ scores) {
  int b = blockIdx.y;
  int k = blockIdx.x * 256 + threadIdx.x;
  __shared__ float Qr[UU][DD];
  for (int li = threadIdx.x; li < UU * DD; li += 256) {
    int u = li >> 6, d = li & 63;
    Qr[u][d] = Q[((size_t)b * LL + topi[b * UU + u]) * DD + d];
  }
  __syncthreads();
  float4 kr[16];
  const float4* Krow = (const float4*)(K + ((size_t)b * LL + k) * DD);
#pragma unroll
  for (int i = 0; i < 16; ++i) kr[i] = Krow[i];
  for (int u = 0; u < UU; ++u) {
    float s = 0.f;
#pragma unroll
    for (int i = 0; i < 16; ++i) {
      float4 qv = *(const float4*)&Qr[u][i << 2];
      s += qv.x * kr[i].x + qv.y * kr[i].y + qv.z * kr[i].z + qv.w * kr[i].w;
    }
    scores[((size_t)(b * UU + u)) * LL + k] = s * 0.125f;
  }
}

__global__ __launch_bounds__(256) void softmax_pv_kernel(const float* __restrict__ scores,
                                                         const float* __restrict__ V,
                                                         float* __restrict__ out) {
  int b = blockIdx.y;
  int u0 = blockIdx.x * 4;
  int tid = threadIdx.x;
  __shared__ float p[4][LL];
  __shared__ float wred[4];
  __shared__ float inv_s[4];
  __shared__ float r2[256];
#pragma unroll
  for (int uu = 0; uu < 4; ++uu) {
    const float* srow = scores + ((size_t)(b * UU + u0 + uu)) * LL;
    float m = NEG_BIG;
    for (int j = tid; j < LL; j += 256) m = fmaxf(m, srow[j]);
#pragma unroll
    for (int off = 32; off > 0; off >>= 1) m = fmaxf(m, __shfl_down(m, off));
    if ((tid & 63) == 0) wred[tid >> 6] = m;
    __syncthreads();
    float smax = fmaxf(fmaxf(wred[0], wred[1]), fmaxf(wred[2], wred[3]));
    __syncthreads();
    float ls = 0.f;
    for (int j = tid; j < LL; j += 256) {
      float e = __expf(srow[j] - smax);
      p[uu][j] = e;
      ls += e;
    }
#pragma unroll
    for (int off = 32; off > 0; off >>= 1) ls += __shfl_down(ls, off);
    if ((tid & 63) == 0) wred[tid >> 6] = ls;
    __syncthreads();
    if (tid == 0) inv_s[uu] = 1.0f / (wred[0] + wred[1] + wred[2] + wred[3]);
    __syncthreads();
  }
  int d = tid & 63, c = tid >> 6;
  float acc[4] = {0.f, 0.f, 0.f, 0.f};
  const float* Vb = V + (size_t)b * LL * DD;
  int k0 = c * (LL / 4), k1 = k0 + (LL / 4);
  for (int k = k0; k < k1; ++k) {
    float v = Vb[(size_t)k * DD + d];
#pragma unroll
    for (int uu = 0; uu < 4; ++uu) acc[uu] += p[uu][k] * v;
  }
#pragma unroll
  for (int uu = 0; uu < 4; ++uu) {
    r2[tid] = acc[uu];
    __syncthreads();
    if (c == 0) {
      out[((size_t)(b * UU) + u0 + uu) * DD + d] =
          (r2[d] + r2[64 + d] + r2[128 + d] + r2[192 + d]) * inv_s[uu];
    }
    __syncthreads();
  }
}

// ---------------------------------------------------------------------------
extern "C" void kernel_launch(void* const* d_in, const int* in_sizes, int n_in,
                              void* d_out, int out_size, void* d_ws, size_t ws_size,
                              hipStream_t stream) {
  (void)in_sizes; (void)n_in; (void)out_size;
  const float* Q = (const float*)d_in[0];
  const float* K = (const float*)d_in[1];
  const float* V = (const float*)d_in[2];
  const int* idx = (const int*)d_in[3];

  float* out = (float*)d_out;
  float* scores = out + (size_t)BB * UU * DD;

  // fast-path workspace layout (~8.7 MB)
  const size_t kg_off = 0;  // Kg bf16: 8 MB; Opart/lpart alias it after mfma_m
  const size_t kpart_off = kg_off + (size_t)BB * LL * DD * sizeof(ushort_t);
  const size_t mb_off = kpart_off + (size_t)BB * 16 * DD * sizeof(float);
  const size_t mpart_off = mb_off + (size_t)BB * LL * sizeof(float);
  const size_t cand_off = mpart_off + (size_t)BB * CC * FSEG * sizeof(float);
  const size_t topi_off = cand_off + (size_t)BB * CC * sizeof(int);
  const size_t need = topi_off + (size_t)BB * UU * sizeof(int);

  char* ws = (char*)d_ws;
  if (ws_size >= need) {
    ushort_t* Kg = (ushort_t*)(ws + kg_off);
    float* Kpart = (float*)(ws + kpart_off);
    float* Mb = (float*)(ws + mb_off);
    float* Mpart = (float*)(ws + mpart_off);
    int* cand = (int*)(ws + cand_off);
    int* topi = (int*)(ws + topi_off);
    // Opart (5.24 MB) + lpart alias the Kg region (dead after mfma_m).
    float* Opart = (float*)(ws + kg_off);
    float* lpart = Opart + (size_t)BB * FSEG * UU * DD;

    prep_ksum_kernel<<<dim3(16, BB), 256, 0, stream>>>(K, idx, Kg, Kpart);
    mfma_m_kernel<<<dim3(LL / 128, BB), 256, 0, stream>>>(Q, Kg, Kpart, Mb);
    cand_kernel<<<BB, 256, 0, stream>>>(Mb, cand);
    rescue_kernel<<<dim3(FSEG, BB), 256, 0, stream>>>(Q, K, idx, cand, Mpart);
    select_kernel<<<BB, 64, 0, stream>>>(Q, Kpart, cand, Mpart, topi);
    fused_epilogue_kernel<<<dim3(FSEG, BB), 256, 0, stream>>>(Q, K, V, topi, scores,
                                                              Opart, lpart);
    combine_kernel<<<BB, 256, 0, stream>>>(Opart, lpart, out);
  } else {
    // fp32 fallback (round-2 path), aliasing dead d_out regions
    size_t need2 =
        (size_t)(BB * LL + BB * 16 * DD) * sizeof(float) + (size_t)(BB * UU) * sizeof(int);
    float* M;
    float* Kpart;
    int* topi;
    if (ws_size >= need2) {
      M = (float*)d_ws;
      Kpart = M + BB * LL;
      topi = (int*)(Kpart + BB * 16 * DD);
    } else {
      M = scores;
      Kpart = scores + BB * LL;
      topi = (int*)out;
    }
    ksum_kernel<<<dim3(16, BB), 256, 0, stream>>>(K, idx, Kpart);
    m_kernel<<<dim3(LL / 128, BB), 256, 0, stream>>>(Q, K, idx, Kpart, M);
    topk_kernel<<<BB, 256, 0, stream>>>(M, topi);
    scores_kernel<<<dim3(LL / 256, BB), 256, 0, stream>>>(Q, K, topi, scores);
    softmax_pv_kernel<<<dim3(UU / 4, BB), 256, 0, stream>>>(scores, V, out);
  }
}

// Round 7
// 219.987 us; speedup vs baseline: 1.4212x; 1.1475x over previous
//
#include <hip/hip_runtime.h>
#include <math.h>

#define BB 32
#define LL 2048
#define DD 64
#define UU 40
#define CC 64            // bf16-phase candidates per batch
#define FSEG 16          // epilogue/rescue key segments (128 keys each)
#define PSTR 42          // pT row stride (floats); even -> 8B-aligned b64 ops
#define NEG_BIG (-3.0e38f)

typedef __attribute__((ext_vector_type(8))) short short8;
typedef __attribute__((ext_vector_type(4))) float f32x4;
typedef unsigned long long ull;
typedef unsigned int uint;
typedef unsigned short ushort_t;

__device__ __forceinline__ unsigned short f2bf(float f) {
  uint u = __float_as_uint(f);
  u += 0x7FFFu + ((u >> 16) & 1u);   // RNE
  return (unsigned short)(u >> 16);
}
__device__ __forceinline__ uint fsort(float f) {
  uint u = __float_as_uint(f);
  return (u & 0x80000000u) ? ~u : (u | 0x80000000u);  // monotonic map
}
__device__ __forceinline__ ull shfl_xor_u64(ull x, int m) {
  uint lo = (uint)x, hi = (uint)(x >> 32);
  lo = __shfl_xor(lo, m);
  hi = __shfl_xor(hi, m);
  return ((ull)hi << 32) | lo;
}
__device__ __forceinline__ int4 pack_bf16x8(float4 a, float4 c4) {
  int4 o;
  o.x = (int)(f2bf(a.x) | ((uint)f2bf(a.y) << 16));
  o.y = (int)(f2bf(a.z) | ((uint)f2bf(a.w) << 16));
  o.z = (int)(f2bf(c4.x) | ((uint)f2bf(c4.y) << 16));
  o.w = (int)(f2bf(c4.z) | ((uint)f2bf(c4.w) << 16));
  return o;
}

// ---------------------------------------------------------------------------
// Kernel 1: gathered K -> bf16 (Kg) + partial Ksum (Kpart) in one pass.
// ---------------------------------------------------------------------------
__global__ __launch_bounds__(256) void prep_ksum_kernel(const float* __restrict__ K,
                                                        const int* __restrict__ idx,
                                                        ushort_t* __restrict__ Kg,
                                                        float* __restrict__ Kpart) {
  int p = blockIdx.x, b = blockIdx.y, t = threadIdx.x;
  int g = t & 7;  // 16B group = 8 elements
  float4 sa = {0.f, 0.f, 0.f, 0.f}, sb = {0.f, 0.f, 0.f, 0.f};
#pragma unroll
  for (int it = 0; it < 4; ++it) {
    int r = p * 128 + it * 32 + (t >> 3);
    int gk = idx[r];
    const float* src = K + ((size_t)b * LL + gk) * DD + g * 8;
    float4 a = *(const float4*)src;
    float4 c4 = *(const float4*)(src + 4);
    sa.x += a.x; sa.y += a.y; sa.z += a.z; sa.w += a.w;
    sb.x += c4.x; sb.y += c4.y; sb.z += c4.z; sb.w += c4.w;
    *(int4*)(Kg + ((size_t)b * LL + r) * DD + g * 8) = pack_bf16x8(a, c4);
  }
  __shared__ float red[32][64];
  int rt = t >> 3;
  *(float4*)&red[rt][g * 8] = sa;
  *(float4*)&red[rt][g * 8 + 4] = sb;
  __syncthreads();
  if (t < 64) {
    float s = 0.f;
#pragma unroll
    for (int r = 0; r < 32; ++r) s += red[r][t];
    Kpart[(b * 16 + p) * 64 + t] = s;
  }
}

// ---------------------------------------------------------------------------
// Kernel 2: bf16 MFMA M-scores. Q converted inline during staging; K from Kg.
// Mb[b][q] = max_j(Q.K_sample[j]) - (Q.Ksum)/L.
// ---------------------------------------------------------------------------
__global__ __launch_bounds__(256) void mfma_m_kernel(const float* __restrict__ Q,
                                                     const ushort_t* __restrict__ Kg,
                                                     const float* __restrict__ Kpart,
                                                     float* __restrict__ Mb) {
  __shared__ __align__(16) ushort_t Qs[128 * 64];  // 16 KB, swizzled
  __shared__ __align__(16) ushort_t Ks[128 * 64];  // 16 KB, swizzled
  __shared__ float Mmax[2][128];
  __shared__ float KsumS[64];

  int b = blockIdx.y, q0 = blockIdx.x * 128;
  int t = threadIdx.x;
  int w = t >> 6, L = t & 63;

  if (t < 64) {
    float s = 0.f;
#pragma unroll
    for (int p = 0; p < 16; ++p) s += Kpart[(b * 16 + p) * 64 + t];
    KsumS[t] = s;
  }

  // stage Q tile once: read fp32, convert to bf16, swizzled store
  {
    int g = t & 7;
#pragma unroll
    for (int it = 0; it < 4; ++it) {
      int r = it * 32 + (t >> 3);
      const float* src = Q + ((size_t)b * LL + q0 + r) * DD + g * 8;
      float4 a = *(const float4*)src;
      float4 c4 = *(const float4*)(src + 4);
      *(int4*)&Qs[r * 64 + 8 * (g ^ (r & 7))] = pack_bf16x8(a, c4);
    }
  }

  f32x4 mx[4];
#pragma unroll
  for (int i = 0; i < 4; ++i) mx[i] = (f32x4){NEG_BIG, NEG_BIG, NEG_BIG, NEG_BIG};

  const int waveQ = 64 * (w & 1);
  const int waveK = 64 * (w >> 1);
  const int lm = L & 15;
  const int lq = L >> 4;

  for (int c = 0; c < LL / 128; ++c) {
    __syncthreads();
    {
      int g = t & 7;
#pragma unroll
      for (int it = 0; it < 4; ++it) {
        int r = it * 32 + (t >> 3);
        int4 v = *(const int4*)(Kg + ((size_t)b * LL + c * 128 + r) * DD + g * 8);
        *(int4*)&Ks[r * 64 + 8 * (g ^ (r & 7))] = v;
      }
    }
    __syncthreads();

    f32x4 acc[4][4];
#pragma unroll
    for (int i = 0; i < 4; ++i)
#pragma unroll
      for (int j = 0; j < 4; ++j) acc[i][j] = (f32x4){0.f, 0.f, 0.f, 0.f};

#pragma unroll
    for (int s = 0; s < 2; ++s) {
      int g = 4 * s + lq;
      short8 A[4];
#pragma unroll
      for (int qt = 0; qt < 4; ++qt) {
        int r = waveQ + 16 * qt + lm;
        A[qt] = *(const short8*)&Qs[r * 64 + 8 * (g ^ (r & 7))];
      }
#pragma unroll
      for (int kt = 0; kt < 4; ++kt) {
        int rB = waveK + 16 * kt + lm;
        short8 Bf = *(const short8*)&Ks[rB * 64 + 8 * (g ^ (rB & 7))];
#pragma unroll
        for (int qt = 0; qt < 4; ++qt) {
          acc[qt][kt] = __builtin_amdgcn_mfma_f32_16x16x32_bf16(A[qt], Bf, acc[qt][kt], 0, 0, 0);
        }
      }
    }
#pragma unroll
    for (int qt = 0; qt < 4; ++qt)
#pragma unroll
      for (int kt = 0; kt < 4; ++kt) {
#pragma unroll
        for (int r4 = 0; r4 < 4; ++r4) mx[qt][r4] = fmaxf(mx[qt][r4], acc[qt][kt][r4]);
      }
  }

#pragma unroll
  for (int qt = 0; qt < 4; ++qt) {
#pragma unroll
    for (int r4 = 0; r4 < 4; ++r4) {
      float v = mx[qt][r4];
      v = fmaxf(v, __shfl_xor(v, 1));
      v = fmaxf(v, __shfl_xor(v, 2));
      v = fmaxf(v, __shfl_xor(v, 4));
      v = fmaxf(v, __shfl_xor(v, 8));
      mx[qt][r4] = v;
    }
  }
  if (lm < 4) {
    int qt = lm;
#pragma unroll
    for (int r4 = 0; r4 < 4; ++r4) {
      Mmax[w >> 1][waveQ + 16 * qt + 4 * lq + r4] = mx[qt][r4];
    }
  }
  __syncthreads();

  if (t < 128) {
    float m = fmaxf(Mmax[0][t], Mmax[1][t]);
    const float4* Qr = (const float4*)(Q + ((size_t)b * LL + q0 + t) * DD);
    float s = 0.f;
#pragma unroll
    for (int i = 0; i < 16; ++i) {
      float4 qv = Qr[i];
      s += qv.x * KsumS[4 * i] + qv.y * KsumS[4 * i + 1] + qv.z * KsumS[4 * i + 2] +
           qv.w * KsumS[4 * i + 3];
    }
    Mb[b * LL + q0 + t] = m - s * (1.0f / (float)LL);
  }
}

// ---------------------------------------------------------------------------
// Kernel 3: per-batch top-64 candidate set by Mb (set only; any order).
// ---------------------------------------------------------------------------
__global__ __launch_bounds__(256) void cand_kernel(const float* __restrict__ Mb,
                                                   int* __restrict__ cand) {
  int b = blockIdx.x, t = threadIdx.x;
  int w = t >> 6;
  float v[8];
#pragma unroll
  for (int i = 0; i < 8; ++i) v[i] = Mb[b * LL + t + 256 * i];
  __shared__ ull warr[4];
  __shared__ ull winls;
  for (int round = 0; round < CC; ++round) {
    float bv = v[0];
    int bi = 0;
#pragma unroll
    for (int i = 1; i < 8; ++i)
      if (v[i] > bv) { bv = v[i]; bi = i; }
    ull key = ((ull)fsort(bv) << 32) | (ull)(uint)(t + 256 * bi);
#pragma unroll
    for (int m = 1; m < 64; m <<= 1) {
      ull o = shfl_xor_u64(key, m);
      if (o > key) key = o;
    }
    if ((t & 63) == 0) warr[w] = key;
    __syncthreads();
    if (t == 0) {
      ull k = warr[0];
#pragma unroll
      for (int i = 1; i < 4; ++i)
        if (warr[i] > k) k = warr[i];
      winls = k;
      cand[b * CC + round] = (int)(k & 0xFFFFFFFFull);
    }
    __syncthreads();
    int wj = (int)(winls & 0xFFFFFFFFull);
    if (t == (wj & 255)) v[wj >> 8] = NEG_BIG;
  }
}

// ---------------------------------------------------------------------------
// Kernel 4: fp32 rescue partial maxes — register-tiled GEMM-max (r2 m_kernel
// pattern). Block (seg, b): 64 candidates x 128 gathered keys; thread
// (tx=t&7, ty=t>>3) computes 8u x 4k dots over d; max folded in registers,
// single LDS reduction at the end. fmaf chain order matches r6 (bit-identical).
// ---------------------------------------------------------------------------
__global__ __launch_bounds__(256) void rescue_kernel(const float* __restrict__ Q,
                                                     const float* __restrict__ K,
                                                     const int* __restrict__ idx,
                                                     const int* __restrict__ cand,
                                                     float* __restrict__ Mpart) {
  __shared__ float Qc[64][68];    // 17408 B
  __shared__ float Kt[128][68];   // 34816 B
  __shared__ float red[64][33];   // 8448 B
  __shared__ int cidx[CC];
  int seg = blockIdx.x, b = blockIdx.y, t = threadIdx.x;

  if (t < CC) cidx[t] = cand[b * CC + t];
  __syncthreads();
  // stage Qc: 64 candidate rows (row = 16 lanes x 16 B, coalesced)
  for (int li = t; li < 64 * 16; li += 256) {
    int row = li >> 4, g4 = li & 15;
    *(float4*)&Qc[row][4 * g4] =
        *(const float4*)(Q + ((size_t)b * LL + cidx[row]) * DD + 4 * g4);
  }
  // stage Kt: 128 gathered key rows
  for (int li = t; li < 128 * 16; li += 256) {
    int row = li >> 4, g4 = li & 15;
    int gk = idx[seg * 128 + row];
    *(float4*)&Kt[row][4 * g4] =
        *(const float4*)(K + ((size_t)b * LL + gk) * DD + 4 * g4);
  }
  __syncthreads();

  int tx = t & 7;    // u = tx + 8*i
  int ty = t >> 3;   // k = ty + 32*j
  float acc[8][4];
#pragma unroll
  for (int i = 0; i < 8; ++i)
#pragma unroll
    for (int j = 0; j < 4; ++j) acc[i][j] = 0.f;

#pragma unroll 4
  for (int dd = 0; dd < 64; dd += 4) {
    float4 qf[8];
#pragma unroll
    for (int i = 0; i < 8; ++i) qf[i] = *(const float4*)&Qc[tx + 8 * i][dd];
    float4 kf[4];
#pragma unroll
    for (int j = 0; j < 4; ++j) kf[j] = *(const float4*)&Kt[ty + 32 * j][dd];
#pragma unroll
    for (int i = 0; i < 8; ++i)
#pragma unroll
      for (int j = 0; j < 4; ++j) {
        float d = acc[i][j];
        d = fmaf(qf[i].x, kf[j].x, d);
        d = fmaf(qf[i].y, kf[j].y, d);
        d = fmaf(qf[i].z, kf[j].z, d);
        d = fmaf(qf[i].w, kf[j].w, d);
        acc[i][j] = d;
      }
  }

#pragma unroll
  for (int i = 0; i < 8; ++i) {
    float m = fmaxf(fmaxf(acc[i][0], acc[i][1]), fmaxf(acc[i][2], acc[i][3]));
    red[tx + 8 * i][ty] = m;
  }
  __syncthreads();
  if (t < CC) {
    float m = red[t][0];
#pragma unroll
    for (int tt = 1; tt < 32; ++tt) m = fmaxf(m, red[t][tt]);
    Mpart[((size_t)b * CC + t) * FSEG + seg] = m;
  }
}

// ---------------------------------------------------------------------------
// Kernel 5: exact fp32 M for candidates; top-40 via rank-by-counting.
// Keys distinct (value | 2047-ci) -> rank permutation == lax.top_k order.
// ---------------------------------------------------------------------------
__global__ __launch_bounds__(64) void select_kernel(const float* __restrict__ Q,
                                                    const float* __restrict__ Kpart,
                                                    const int* __restrict__ cand,
                                                    const float* __restrict__ Mpart,
                                                    int* __restrict__ topi) {
  int b = blockIdx.x, t = threadIdx.x;
  __shared__ float KsumS[64];
  __shared__ ull keys[CC];
  {
    float s = 0.f;
#pragma unroll
    for (int p = 0; p < 16; ++p) s += Kpart[(b * 16 + p) * 64 + t];
    KsumS[t] = s;
  }
  __syncthreads();
  int ci = cand[b * CC + t];
  float m = NEG_BIG;
#pragma unroll
  for (int s = 0; s < FSEG; ++s) m = fmaxf(m, Mpart[((size_t)b * CC + t) * FSEG + s]);
  const float4* Qr = (const float4*)(Q + ((size_t)b * LL + ci) * DD);
  float s = 0.f;
#pragma unroll
  for (int i = 0; i < 16; ++i) {
    float4 qv = Qr[i];
    s += qv.x * KsumS[4 * i] + qv.y * KsumS[4 * i + 1] + qv.z * KsumS[4 * i + 2] +
         qv.w * KsumS[4 * i + 3];
  }
  float Mf = m - s * (1.0f / (float)LL);
  ull key = ((ull)fsort(Mf) << 32) | (ull)(uint)(2047 - ci);
  keys[t] = key;
  __syncthreads();
  int rank = 0;
#pragma unroll 8
  for (int j = 0; j < CC; ++j) rank += (keys[j] > key) ? 1 : 0;
  if (rank < UU) topi[b * UU + rank] = ci;
}

// ---------------------------------------------------------------------------
// Kernel 6: FUSED epilogue per (seg, b), 128 keys/seg: scores (exact fp32
// output) + exp (no max subtraction; |s|<~6 safe) + per-seg exp-sum +
// partial P.V. LDS Qc broadcast feed; thread (kl, uh) does 20 u's each.
// ---------------------------------------------------------------------------
__global__ __launch_bounds__(256, 2) void fused_epilogue_kernel(
    const float* __restrict__ Q, const float* __restrict__ K,
    const float* __restrict__ V, const int* __restrict__ topi,
    float* __restrict__ scores, float* __restrict__ Opart,
    float* __restrict__ lpart) {
  int seg = blockIdx.x, b = blockIdx.y, t = threadIdx.x;
  __shared__ int cidx[UU];
  __shared__ float Qc[UU][DD];       // 10240 B
  __shared__ float pT[128 * PSTR];   // 21504 B; aliased as red[2][40][64]
  __shared__ float lw[4][20];        // 320 B

  if (t < UU) cidx[t] = topi[b * UU + t];
  __syncthreads();
  for (int li = t; li < UU * 16; li += 256) {
    int u = li >> 4, g4 = li & 15;
    *(float4*)&Qc[u][4 * g4] =
        *(const float4*)(Q + ((size_t)b * LL + cidx[u]) * DD + 4 * g4);
  }
  __syncthreads();

  // ---- Phase A: scores + exp. thread (kl = t&127, uh = t>>7) ----
  int kl = t & 127, uh = t >> 7, w = t >> 6;
  int k = seg * 128 + kl;
  float4 kr[16];
  const float4* Krow = (const float4*)(K + ((size_t)b * LL + k) * DD);
#pragma unroll
  for (int i = 0; i < 16; ++i) kr[i] = Krow[i];

  float p[20];
#pragma unroll 4
  for (int j = 0; j < 20; ++j) {
    int u = uh * 20 + j;
    const float4* qp = (const float4*)&Qc[u][0];
    float s = 0.f;
#pragma unroll
    for (int i = 0; i < 16; ++i) {
      float4 qv = qp[i];  // broadcast LDS read
      s += qv.x * kr[i].x + qv.y * kr[i].y + qv.z * kr[i].z + qv.w * kr[i].w;
    }
    s *= 0.125f;
    scores[((size_t)(b * UU + u)) * LL + k] = s;
    p[j] = __expf(s);
  }

  // ---- Phase B: per-seg exp-sums (wave = 64 keys) + transpose p ----
#pragma unroll
  for (int j = 0; j < 20; ++j) {
    float ls = p[j];
#pragma unroll
    for (int off = 32; off > 0; off >>= 1) ls += __shfl_xor(ls, off);
    if ((t & 63) == 0) lw[w][j] = ls;
  }
#pragma unroll
  for (int j = 0; j < 20; j += 2) {
    *(float2*)&pT[kl * PSTR + uh * 20 + j] = make_float2(p[j], p[j + 1]);
  }
  __syncthreads();
  if (t < UU) {
    int u = t;
    float ls = (u < 20) ? (lw[0][u] + lw[1][u]) : (lw[2][u - 20] + lw[3][u - 20]);
    lpart[(size_t)(b * FSEG + seg) * UU + u] = ls;
  }

  // ---- Phase C: partial P.V ----
  // thread (d4 = t&15, c = t>>4): ug = c&7 -> 5 u's, kq = c>>3 -> 64 keys.
  int d4 = t & 15, c = t >> 4;
  int ug = c & 7, kq = c >> 3;
  int u0 = ug * 5;
  float4 acc[5];
#pragma unroll
  for (int j = 0; j < 5; ++j) acc[j] = (float4){0.f, 0.f, 0.f, 0.f};
  const float* Vb = V + ((size_t)b * LL + seg * 128 + kq * 64) * DD;
  for (int kk = 0; kk < 64; ++kk) {
    float4 v4 = *(const float4*)(Vb + (size_t)kk * DD + 4 * d4);
    const float* prow = &pT[(kq * 64 + kk) * PSTR + u0];
#pragma unroll
    for (int j = 0; j < 5; ++j) {
      float pj = prow[j];
      acc[j].x += pj * v4.x; acc[j].y += pj * v4.y;
      acc[j].z += pj * v4.z; acc[j].w += pj * v4.w;
    }
  }
  __syncthreads();  // all pT reads done before aliasing as red
  float* red = pT;  // red[kq][u][d] = red[(kq*40+u)*64 + d], 20480 B
#pragma unroll
  for (int j = 0; j < 5; ++j)
    *(float4*)&red[(kq * 40 + u0 + j) * 64 + 4 * d4] = acc[j];
  __syncthreads();
  for (int li = t; li < UU * DD; li += 256) {
    int u = li >> 6, d = li & 63;
    float s = red[u * 64 + d] + red[(40 + u) * 64 + d];
    Opart[((size_t)(b * FSEG + seg) * UU + u) * DD + d] = s;
  }
}

// ---------------------------------------------------------------------------
// Kernel 7: combine segments: out = (sum_s Opart) / (sum_s lpart).
// ---------------------------------------------------------------------------
__global__ __launch_bounds__(256) void combine_kernel(const float* __restrict__ Opart,
                                                      const float* __restrict__ lpart,
                                                      float* __restrict__ out) {
  int b = blockIdx.x, t = threadIdx.x;
  __shared__ float Linv[UU];
  if (t < UU) {
    float Lsum = 0.f;
#pragma unroll
    for (int s = 0; s < FSEG; ++s) Lsum += lpart[(size_t)(b * FSEG + s) * UU + t];
    Linv[t] = 1.0f / Lsum;
  }
  __syncthreads();
  for (int li = t; li < UU * DD; li += 256) {
    int u = li >> 6, d = li & 63;
    float O = 0.f;
#pragma unroll
    for (int s = 0; s < FSEG; ++s)
      O += Opart[((size_t)(b * FSEG + s) * UU + u) * DD + d];
    out[((size_t)b * UU + u) * DD + d] = O * Linv[u];
  }
}

// ========================= fp32 fallback (round-2 path) ====================
__global__ __launch_bounds__(256) void ksum_kernel(const float* __restrict__ K,
                                                   const int* __restrict__ idx,
                                                   float* __restrict__ Kpart) {
  int p = blockIdx.x, b = blockIdx.y, tid = threadIdx.x;
  int d = tid & 63, c = tid >> 6;
  const float* Kb = K + (size_t)b * LL * DD;
  float acc = 0.f;
  int j0 = p * 128 + c * 32;
#pragma unroll 4
  for (int t = 0; t < 32; ++t) acc += Kb[(size_t)idx[j0 + t] * DD + d];
  __shared__ float red[256];
  red[tid] = acc;
  __syncthreads();
  if (c == 0) Kpart[(b * 16 + p) * 64 + d] = red[d] + red[64 + d] + red[128 + d] + red[192 + d];
}

__global__ __launch_bounds__(256) void m_kernel(const float* __restrict__ Q,
                                                const float* __restrict__ K,
                                                const int* __restrict__ idx,
                                                const float* __restrict__ Kpart,
                                                float* __restrict__ M) {
  __shared__ float Qs[128][68];
  __shared__ float Ks[128][68];
  __shared__ float KsumS[64];
  __shared__ float red[128][17];
  int b = blockIdx.y, q0 = blockIdx.x * 128, tid = threadIdx.x;
  int tx = tid & 15, ty = tid >> 4;
  if (tid < 64) {
    float s = 0.f;
#pragma unroll
    for (int p = 0; p < 16; ++p) s += Kpart[(b * 16 + p) * 64 + tid];
    KsumS[tid] = s;
  }
#pragma unroll
  for (int it = 0; it < 8; ++it) {
    int li = it * 256 + tid;
    int q = li >> 4, dd = (li & 15) << 2;
    *(float4*)&Qs[q][dd] = *(const float4*)(Q + ((size_t)b * LL + q0 + q) * DD + dd);
  }
  float mx[8];
#pragma unroll
  for (int i = 0; i < 8; ++i) mx[i] = NEG_BIG;
  for (int c = 0; c < LL / 128; ++c) {
    __syncthreads();
#pragma unroll
    for (int it = 0; it < 8; ++it) {
      int li = it * 256 + tid;
      int kk = li >> 4, dd = (li & 15) << 2;
      int gk = idx[c * 128 + kk];
      *(float4*)&Ks[kk][dd] = *(const float4*)(K + ((size_t)b * LL + gk) * DD + dd);
    }
    __syncthreads();
    float acc[8][8];
#pragma unroll
    for (int i = 0; i < 8; ++i)
#pragma unroll
      for (int j = 0; j < 8; ++j) acc[i][j] = 0.f;
#pragma unroll 2
    for (int dd = 0; dd < 64; dd += 4) {
      float4 qf[8];
#pragma unroll
      for (int i = 0; i < 8; ++i) qf[i] = *(const float4*)&Qs[tx + 16 * i][dd];
#pragma unroll
      for (int j = 0; j < 8; ++j) {
        float4 kf = *(const float4*)&Ks[ty + 16 * j][dd];
#pragma unroll
        for (int i = 0; i < 8; ++i)
          acc[i][j] += qf[i].x * kf.x + qf[i].y * kf.y + qf[i].z * kf.z + qf[i].w * kf.w;
      }
    }
#pragma unroll
    for (int i = 0; i < 8; ++i) {
      float m01 = fmaxf(fmaxf(acc[i][0], acc[i][1]), fmaxf(acc[i][2], acc[i][3]));
      float m23 = fmaxf(fmaxf(acc[i][4], acc[i][5]), fmaxf(acc[i][6], acc[i][7]));
      mx[i] = fmaxf(mx[i], fmaxf(m01, m23));
    }
  }
  __syncthreads();
#pragma unroll
  for (int i = 0; i < 8; ++i) red[tx + 16 * i][ty] = mx[i];
  __syncthreads();
  if (tid < 128) {
    float m = red[tid][0];
#pragma unroll
    for (int tt = 1; tt < 16; ++tt) m = fmaxf(m, red[tid][tt]);
    float s = 0.f;
#pragma unroll 16
    for (int d = 0; d < 64; ++d) s += Qs[tid][d] * KsumS[d];
    M[b * LL + q0 + tid] = m - s * (1.0f / (float)LL);
  }
}

__global__ __launch_bounds__(256) void topk_kernel(const float* __restrict__ M,
                                                   int* __restrict__ topi) {
  int b = blockIdx.x, tid = threadIdx.x;
  __shared__ float mv[LL];
  __shared__ float wv[4];
  __shared__ int wi[4];
  for (int j = tid; j < LL; j += 256) mv[j] = M[b * LL + j];
  __syncthreads();
  for (int t = 0; t < UU; ++t) {
    float bv = NEG_BIG;
    int bi = 0x7fffffff;
    for (int j = tid; j < LL; j += 256) {
      float v = mv[j];
      if (v > bv) { bv = v; bi = j; }
    }
#pragma unroll
    for (int off = 32; off > 0; off >>= 1) {
      float ov = __shfl_down(bv, off);
      int oi = __shfl_down(bi, off);
      if (ov > bv || (ov == bv && oi < bi)) { bv = ov; bi = oi; }
    }
    if ((tid & 63) == 0) { wv[tid >> 6] = bv; wi[tid >> 6] = bi; }
    __syncthreads();
    if (tid == 0) {
#pragma unroll
      for (int w = 1; w < 4; ++w)
        if (wv[w] > bv || (wv[w] == bv && wi[w] < bi)) { bv = wv[w]; bi = wi[w]; }
      topi[b * UU + t] = bi;
      mv[bi] = NEG_BIG;
    }
    __syncthreads();
  }
}

__global__ __launch_bounds__(256) void scores_kernel(const float* __restrict__ Q,
                                                     const float* __restrict__ K,
                                                     const int* __restrict__ topi,
                                                     float* __restrict__ scores) {
  int b = blockIdx.y;
  int k = blockIdx.x * 256 + threadIdx.x;
  __shared__ float Qr[UU][DD];
  for (int li = threadIdx.x; li < UU * DD; li += 256) {
    int u = li >> 6, d = li & 63;
    Qr[u][d] = Q[((size_t)b * LL + topi[b * UU + u]) * DD + d];
  }
  __syncthreads();
  float4 kr[16];
  const float4* Krow = (const float4*)(K + ((size_t)b * LL + k) * DD);
#pragma unroll
  for (int i = 0; i < 16; ++i) kr[i] = Krow[i];
  for (int u = 0; u < UU; ++u) {
    float s = 0.f;
#pragma unroll
    for (int i = 0; i < 16; ++i) {
      float4 qv = *(const float4*)&Qr[u][i << 2];
      s += qv.x * kr[i].x + qv.y * kr[i].y + qv.z * kr[i].z + qv.w * kr[i].w;
    }
    scores[((size_t)(b * UU + u)) * LL + k] = s * 0.125f;
  }
}

__global__ __launch_bounds__(256) void softmax_pv_kernel(const float* __restrict__ scores,
                                                         const float* __restrict__ V,
                                                         float* __restrict__ out) {
  int b = blockIdx.y;
  int u0 = blockIdx.x * 4;
  int tid = threadIdx.x;
  __shared__ float p[4][LL];
  __shared__ float wred[4];
  __shared__ float inv_s[4];
  __shared__ float r2[256];
#pragma unroll
  for (int uu = 0; uu < 4; ++uu) {
    const float* srow = scores + ((size_t)(b * UU + u0 + uu)) * LL;
    float m = NEG_BIG;
    for (int j = tid; j < LL; j += 256) m = fmaxf(m, srow[j]);
#pragma unroll
    for (int off = 32; off > 0; off >>= 1) m = fmaxf(m, __shfl_down(m, off));
    if ((tid & 63) == 0) wred[tid >> 6] = m;
    __syncthreads();
    float smax = fmaxf(fmaxf(wred[0], wred[1]), fmaxf(wred[2], wred[3]));
    __syncthreads();
    float ls = 0.f;
    for (int j = tid; j < LL; j += 256) {
      float e = __expf(srow[j] - smax);
      p[uu][j] = e;
      ls += e;
    }
#pragma unroll
    for (int off = 32; off > 0; off >>= 1) ls += __shfl_down(ls, off);
    if ((tid & 63) == 0) wred[tid >> 6] = ls;
    __syncthreads();
    if (tid == 0) inv_s[uu] = 1.0f / (wred[0] + wred[1] + wred[2] + wred[3]);
    __syncthreads();
  }
  int d = tid & 63, c = tid >> 6;
  float acc[4] = {0.f, 0.f, 0.f, 0.f};
  const float* Vb = V + (size_t)b * LL * DD;
  int k0 = c * (LL / 4), k1 = k0 + (LL / 4);
  for (int k = k0; k < k1; ++k) {
    float v = Vb[(size_t)k * DD + d];
#pragma unroll
    for (int uu = 0; uu < 4; ++uu) acc[uu] += p[uu][k] * v;
  }
#pragma unroll
  for (int uu = 0; uu < 4; ++uu) {
    r2[tid] = acc[uu];
    __syncthreads();
    if (c == 0) {
      out[((size_t)(b * UU) + u0 + uu) * DD + d] =
          (r2[d] + r2[64 + d] + r2[128 + d] + r2[192 + d]) * inv_s[uu];
    }
    __syncthreads();
  }
}

// ---------------------------------------------------------------------------
extern "C" void kernel_launch(void* const* d_in, const int* in_sizes, int n_in,
                              void* d_out, int out_size, void* d_ws, size_t ws_size,
                              hipStream_t stream) {
  (void)in_sizes; (void)n_in; (void)out_size;
  const float* Q = (const float*)d_in[0];
  const float* K = (const float*)d_in[1];
  const float* V = (const float*)d_in[2];
  const int* idx = (const int*)d_in[3];

  float* out = (float*)d_out;
  float* scores = out + (size_t)BB * UU * DD;

  // fast-path workspace layout (~8.7 MB)
  const size_t kg_off = 0;  // Kg bf16: 8 MB; Opart/lpart alias it after mfma_m
  const size_t kpart_off = kg_off + (size_t)BB * LL * DD * sizeof(ushort_t);
  const size_t mb_off = kpart_off + (size_t)BB * 16 * DD * sizeof(float);
  const size_t mpart_off = mb_off + (size_t)BB * LL * sizeof(float);
  const size_t cand_off = mpart_off + (size_t)BB * CC * FSEG * sizeof(float);
  const size_t topi_off = cand_off + (size_t)BB * CC * sizeof(int);
  const size_t need = topi_off + (size_t)BB * UU * sizeof(int);

  char* ws = (char*)d_ws;
  if (ws_size >= need) {
    ushort_t* Kg = (ushort_t*)(ws + kg_off);
    float* Kpart = (float*)(ws + kpart_off);
    float* Mb = (float*)(ws + mb_off);
    float* Mpart = (float*)(ws + mpart_off);
    int* cand = (int*)(ws + cand_off);
    int* topi = (int*)(ws + topi_off);
    // Opart (5.24 MB) + lpart alias the Kg region (dead after mfma_m).
    float* Opart = (float*)(ws + kg_off);
    float* lpart = Opart + (size_t)BB * FSEG * UU * DD;

    prep_ksum_kernel<<<dim3(16, BB), 256, 0, stream>>>(K, idx, Kg, Kpart);
    mfma_m_kernel<<<dim3(LL / 128, BB), 256, 0, stream>>>(Q, Kg, Kpart, Mb);
    cand_kernel<<<BB, 256, 0, stream>>>(Mb, cand);
    rescue_kernel<<<dim3(FSEG, BB), 256, 0, stream>>>(Q, K, idx, cand, Mpart);
    select_kernel<<<BB, 64, 0, stream>>>(Q, Kpart, cand, Mpart, topi);
    fused_epilogue_kernel<<<dim3(FSEG, BB), 256, 0, stream>>>(Q, K, V, topi, scores,
                                                              Opart, lpart);
    combine_kernel<<<BB, 256, 0, stream>>>(Opart, lpart, out);
  } else {
    // fp32 fallback (round-2 path), aliasing dead d_out regions
    size_t need2 =
        (size_t)(BB * LL + BB * 16 * DD) * sizeof(float) + (size_t)(BB * UU) * sizeof(int);
    float* M;
    float* Kpart;
    int* topi;
    if (ws_size >= need2) {
      M = (float*)d_ws;
      Kpart = M + BB * LL;
      topi = (int*)(Kpart + BB * 16 * DD);
    } else {
      M = scores;
      Kpart = scores + BB * LL;
      topi = (int*)out;
    }
    ksum_kernel<<<dim3(16, BB), 256, 0, stream>>>(K, idx, Kpart);
    m_kernel<<<dim3(LL / 128, BB), 256, 0, stream>>>(Q, K, idx, Kpart, M);
    topk_kernel<<<BB, 256, 0, stream>>>(M, topi);
    scores_kernel<<<dim3(LL / 256, BB), 256, 0, stream>>>(Q, K, topi, scores);
    softmax_pv_kernel<<<dim3(UU / 4, BB), 256, 0, stream>>>(scores, V, out);
  }
}